// Round 7
// baseline (4657.156 us; speedup 1.0000x reference)
//
#include <hip/hip_runtime.h>
#include <hip/hip_bf16.h>

// SCAE forward on MI355X — f16 split-MFMA (Ootomo 3-product) pipeline.
//   v = h + l/2048 (f16 h,l; subnormal-guarded)  =>
//   A@B = Ah@Bh + (Ah@Bl + Al@Bh)/2048   (drop 2^-22 term)
// All GEMMs are A[M][K] x BT[N][K] row-major:
//   G0: approx = x @ W_enc       A=x_pk,   BT=W_encT_pk,   C=f32 +bias2
//   G1: virtT  = W_encT @ uWdT   A=Wt_pk,  BT=up_W_dec_pk, C=packed f16, mask in epilogue
//   G2: approx+= up_feats @ virt A=uf_pk,  BT=virtT_pk,    C=f32 +=
// Then exact radix top-k (ties->lowest index), relu, sparse decode.
//
// R7 (vs R6):
//  - MFMA 16x16x32 -> 32x32x16 (2178 vs 1955 TF ceiling, 24 vs 48 instr/step)
//    C/D: row=(reg&3)+8*(reg>>2)+4*(l>>5), col=l&31 (guide-verified m74/m101)
//  - FC=4096: G2's B panel 134MB -> L3-resident; 512-block grid = one
//    co-resident generation (kills the 2.7x FETCH overfetch seen in R6)
//  - bijective XCD-chunked blockIdx swizzle (all grids % 8 == 0)

#define D_DIM 768
#define F_DIM 8192

typedef _Float16 f16;
typedef _Float16 f16x8 __attribute__((ext_vector_type(8)));
typedef float f32x16 __attribute__((ext_vector_type(16)));

#define BMN 128
#define BUFB 32768    // one K-tile: A 16KB + B 16KB (128 rows x 128B each)
#define PLNB 16384    // per-matrix region: 128 rows x 128B ([h|l] packed, XOR-8 swizzled)

__device__ inline void split_f32(float v, f16& h, f16& l) {
    float hf = (float)(f16)v;
    if (__builtin_fabsf(hf) < 6.1035156e-5f) hf = 0.f;   // keep h MFMA-normal
    h = (f16)hf;
    l = (f16)((v - hf) * 2048.0f);
}

// MODE 0: C = comb + bias[col]             (f32)
// MODE 1: Vp = packed_split(comb * mask)   (f16, row = 2*F_DIM elems)
// MODE 2: C += comb                        (f32)
template<int MODE>
__global__ __launch_bounds__(256, 2)
void mfma_gemm(const f16* __restrict__ Ap,     // packed, row stride 2K f16
               const f16* __restrict__ Bp,     // packed BT, row stride 2K f16
               float* __restrict__ C, int ldc,
               f16* __restrict__ Vp,
               const float* __restrict__ bias,
               const unsigned char* __restrict__ conn, int upIdx,
               const int* __restrict__ flagp,
               int K, int fdBase)
{
    __shared__ char lds[2 * BUFB];   // double-buffered K-tile
    const int tid = threadIdx.x;

    // bijective XCD-chunked swizzle (nwg always a multiple of 8 here)
    const unsigned gx = gridDim.x;
    const unsigned nwg = gx * gridDim.y;
    const unsigned bid0 = blockIdx.y * gx + blockIdx.x;
    const unsigned cpx = nwg >> 3;
    const unsigned bid = (bid0 & 7u) * cpx + (bid0 >> 3);
    const int bm = (int)(bid / gx) * BMN;
    const int bn = (int)(bid % gx) * BMN;

    const int w  = tid >> 6;
    const int l  = tid & 63;
    const int wr = (w >> 1) * 64;   // wave row origin
    const int wc = (w & 1) * 64;    // wave col origin
    const int ln = l & 31;          // row-in-fragment
    const int ls = l >> 5;          // k-group 0/1

    // Staging: 2048 chunks of 16B per K-tile, 8/thread (c = tid + 256j).
    // chunk c: matrix p=c>>10 (0=A,1=B), row r=(c>>3)&127, phys slot sp=c&7.
    // logical slot = sp ^ (r&7) (XOR-8, involution); row source bytes are
    // CONTIGUOUS 128B = [h k-slots 0..3 | l k-slots 4..7]. LDS dest linear.
    const char* gsrc[8];
    #pragma unroll
    for (int j = 0; j < 8; ++j) {
        const int c = tid + 256 * j;
        const int p = c >> 10;
        const int q = c & 1023;
        const int r = q >> 3;
        const int sp = q & 7;
        const int slog = sp ^ (r & 7);
        const f16* base = p ? Bp : Ap;
        const int row0 = p ? bn : bm;
        gsrc[j] = (const char*)base + (size_t)(row0 + r) * ((size_t)K * 4)
                  + slog * 16;
    }

    #define STAGE(BUFSEL)                                                     \
        _Pragma("unroll")                                                     \
        for (int j = 0; j < 8; ++j) {                                         \
            __builtin_amdgcn_global_load_lds(                                 \
                (const __attribute__((address_space(1))) void*)gsrc[j],       \
                (__attribute__((address_space(3))) void*)                     \
                    (lds + (BUFSEL) * BUFB + (tid + 256 * j) * 16),           \
                16, 0, 0);                                                    \
            gsrc[j] += 128;   /* next 32-k packed block */                    \
        }

    f32x16 accH[2][2], accM[2][2];
    #pragma unroll
    for (int a = 0; a < 2; ++a)
        #pragma unroll
        for (int b = 0; b < 2; ++b) {
            accH[a][b] = (f32x16)(0.f);
            accM[a][b] = (f32x16)(0.f);
        }

    const int steps = K >> 5;

    // Hoisted loop-invariant LDS read byte-offsets (XOR-swizzle math ONCE).
    // h slot for k-half kh: kh*2+ls ; l slot: 4+kh*2+ls ; XOR row&7.
    int offAH[2][2], offAL[2][2], offBH[2][2], offBL[2][2];  // [frag][kh]
    #pragma unroll
    for (int f = 0; f < 2; ++f)
        #pragma unroll
        for (int kh = 0; kh < 2; ++kh) {
            const int ra = wr + f * 32 + ln;
            const int rb = wc + f * 32 + ln;
            offAH[f][kh] = ra * 128 + (((kh * 2 + ls) ^ (ra & 7)) * 16);
            offAL[f][kh] = ra * 128 + (((4 + kh * 2 + ls) ^ (ra & 7)) * 16);
            offBH[f][kh] = PLNB + rb * 128 + (((kh * 2 + ls) ^ (rb & 7)) * 16);
            offBL[f][kh] = PLNB + rb * 128 + (((4 + kh * 2 + ls) ^ (rb & 7)) * 16);
        }

    STAGE(0);
    int cur = 0;
    for (int t = 0; t < steps; ++t) {
        // buf[cur]'s loads were issued one phase ago (hidden under MFMAs)
        asm volatile("s_waitcnt vmcnt(0)" ::: "memory");
        __syncthreads();

        const char* Lb = lds + cur * BUFB;
        // ---- read h-fragments (8 reads) ----
        f16x8 ah[2][2], bh[2][2];
        #pragma unroll
        for (int f = 0; f < 2; ++f)
            #pragma unroll
            for (int kh = 0; kh < 2; ++kh) {
                ah[f][kh] = *(const f16x8*)(Lb + offAH[f][kh]);
                bh[f][kh] = *(const f16x8*)(Lb + offBH[f][kh]);
            }

        // ---- stage next tile (drained at next iter's top) ----
        if (t + 1 < steps) STAGE(cur ^ 1);

        // ---- read l-fragments (8 reads; overlap H-MFMAs) ----
        f16x8 al[2][2], bl[2][2];
        #pragma unroll
        for (int f = 0; f < 2; ++f)
            #pragma unroll
            for (int kh = 0; kh < 2; ++kh) {
                bl[f][kh] = *(const f16x8*)(Lb + offBL[f][kh]);
                al[f][kh] = *(const f16x8*)(Lb + offAL[f][kh]);
            }

        // ---- H phase: 8 MFMAs ----
        __builtin_amdgcn_s_setprio(1);
        #pragma unroll
        for (int kh = 0; kh < 2; ++kh)
            #pragma unroll
            for (int nf = 0; nf < 2; ++nf)
                #pragma unroll
                for (int mf = 0; mf < 2; ++mf)
                    accH[mf][nf] = __builtin_amdgcn_mfma_f32_32x32x16_f16(
                        ah[mf][kh], bh[nf][kh], accH[mf][nf], 0, 0, 0);
        __builtin_amdgcn_s_setprio(0);

        // ---- M phase: 16 MFMAs ----
        __builtin_amdgcn_s_setprio(1);
        #pragma unroll
        for (int kh = 0; kh < 2; ++kh)
            #pragma unroll
            for (int nf = 0; nf < 2; ++nf)
                #pragma unroll
                for (int mf = 0; mf < 2; ++mf)
                    accM[mf][nf] = __builtin_amdgcn_mfma_f32_32x32x16_f16(
                        ah[mf][kh], bl[nf][kh], accM[mf][nf], 0, 0, 0);
        #pragma unroll
        for (int kh = 0; kh < 2; ++kh)
            #pragma unroll
            for (int mf = 0; mf < 2; ++mf)
                #pragma unroll
                for (int nf = 0; nf < 2; ++nf)
                    accM[mf][nf] = __builtin_amdgcn_mfma_f32_32x32x16_f16(
                        al[mf][kh], bh[nf][kh], accM[mf][nf], 0, 0, 0);
        __builtin_amdgcn_s_setprio(0);

        cur ^= 1;
    }
    #undef STAGE

    const float MS = 4.8828125e-4f;   // 1/2048
    const int flag = (MODE == 1) ? *flagp : 0;

    // C/D layout (32x32): col = ln, row = (reg&3) + 8*(reg>>2) + 4*ls
    #pragma unroll
    for (int mf = 0; mf < 2; ++mf) {
        #pragma unroll
        for (int nf = 0; nf < 2; ++nf) {
            const int gcol = bn + wc + nf * 32 + ln;
            #pragma unroll
            for (int g = 0; g < 4; ++g) {
                const int row0 = wr + mf * 32 + g * 8 + 4 * ls;  // + (reg&3)
                float v[4];
                #pragma unroll
                for (int rr = 0; rr < 4; ++rr)
                    v[rr] = accH[mf][nf][g * 4 + rr]
                          + accM[mf][nf][g * 4 + rr] * MS;

                if (MODE == 0) {
                    const float bb = bias[gcol];
                    #pragma unroll
                    for (int rr = 0; rr < 4; ++rr)
                        C[(size_t)(bm + row0 + rr) * ldc + gcol] = v[rr] + bb;
                } else if (MODE == 2) {
                    #pragma unroll
                    for (int rr = 0; rr < 4; ++rr) {
                        float* cp = &C[(size_t)(bm + row0 + rr) * ldc + gcol];
                        *cp = *cp + v[rr];
                    }
                } else {
                    const size_t fu = (size_t)gcol;
                    const size_t fd0 = (size_t)(fdBase + bm + row0);
                    int m[4];
                    if (flag == 1) {
                        const int4 mm = *(const int4*)((const int*)conn +
                            (size_t)upIdx * F_DIM * F_DIM + fu * F_DIM + fd0);
                        m[0] = mm.x; m[1] = mm.y; m[2] = mm.z; m[3] = mm.w;
                    } else if (flag == 0) {
                        const uchar4 mm = *(const uchar4*)(conn +
                            (size_t)upIdx * F_DIM * F_DIM + fu * F_DIM + fd0);
                        m[0] = mm.x; m[1] = mm.y; m[2] = mm.z; m[3] = mm.w;
                    } else if (flag == 2) {
                        const long long* pp = (const long long*)conn +
                            (size_t)upIdx * F_DIM * F_DIM + fu * F_DIM + fd0;
                        m[0] = (int)pp[0]; m[1] = (int)pp[1];
                        m[2] = (int)pp[2]; m[3] = (int)pp[3];
                    } else {
                        const float4 mm = *(const float4*)((const float*)conn +
                            (size_t)upIdx * F_DIM * F_DIM + fu * F_DIM + fd0);
                        m[0] = mm.x != 0.f; m[1] = mm.y != 0.f;
                        m[2] = mm.z != 0.f; m[3] = mm.w != 0.f;
                    }
                    // packed write: row fd, k=fu -> fd*2F + (fu>>5)*64 + (fu&31)
                    const size_t kblk = (fu >> 5) * 64 + (fu & 31);
                    #pragma unroll
                    for (int rr = 0; rr < 4; ++rr) {
                        const float vv = m[rr] ? v[rr] : 0.f;
                        f16 hh, ll;
                        split_f32(vv, hh, ll);
                        const size_t o =
                            (size_t)(bm + row0 + rr) * (2 * F_DIM) + kblk;
                        Vp[o] = hh; Vp[o + 32] = ll;
                    }
                }
            }
        }
    }
}

// elementwise split into packed layout: row r of K -> 2K f16, blocks of
// [32 h | 32 l]. 8 contiguous k per thread (stay within one 32-block).
__global__ __launch_bounds__(256)
void split_kernel(const float* __restrict__ src, f16* __restrict__ dst,
                  size_t n, int K)
{
    const size_t e = ((size_t)blockIdx.x * 256 + threadIdx.x) * 8;
    if (e >= n) return;
    const size_t r = e / (size_t)K;
    const int k = (int)(e - r * (size_t)K);
    const float4 a = *(const float4*)(src + e);
    const float4 b = *(const float4*)(src + e + 4);
    f16 hv[8], lv[8];
    const float s[8] = {a.x, a.y, a.z, a.w, b.x, b.y, b.z, b.w};
    #pragma unroll
    for (int i = 0; i < 8; ++i) split_f32(s[i], hv[i], lv[i]);
    const size_t base = r * (size_t)(2 * K) + (size_t)((k >> 5) * 64 + (k & 31));
    *(f16x8*)(dst + base)      = *(const f16x8*)hv;
    *(f16x8*)(dst + base + 32) = *(const f16x8*)lv;
}

// W_enc [768][8192] -> packed W_encT rows f (K=768); reads coalesced along f
__global__ __launch_bounds__(256)
void transpose_split_kernel(const float* __restrict__ W, f16* __restrict__ dst)
{
    const int f = blockIdx.x * 256 + threadIdx.x;
    for (int dc = 0; dc < D_DIM / 8; ++dc) {
        const int k = dc * 8;
        f16 hv[8], lv[8];
        #pragma unroll
        for (int j = 0; j < 8; ++j)
            split_f32(W[(size_t)(k + j) * F_DIM + f], hv[j], lv[j]);
        const size_t base = (size_t)f * (2 * D_DIM) + (k >> 5) * 64 + (k & 31);
        *(f16x8*)(dst + base)      = *(const f16x8*)hv;
        *(f16x8*)(dst + base + 32) = *(const f16x8*)lv;
    }
}

// conn_mask storage-layout detection: 0=u8, 1=i32, 2=i64, 3=f32
__global__ void detect_kernel(const int* __restrict__ conn, int* __restrict__ flag)
{
    __shared__ int not01, notf01, odd_nz;
    if (threadIdx.x == 0) { not01 = 0; notf01 = 0; odd_nz = 0; }
    __syncthreads();
    const int4 v = ((const int4*)conn)[threadIdx.x];
    const unsigned a[4] = {(unsigned)v.x, (unsigned)v.y,
                           (unsigned)v.z, (unsigned)v.w};
    int l_not01 = 0, l_notf = 0;
    #pragma unroll
    for (int i = 0; i < 4; ++i) {
        if (a[i] > 1u) l_not01 = 1;
        if (a[i] != 0u && a[i] != 0x3F800000u) l_notf = 1;
    }
    if (l_not01) atomicOr(&not01, 1);
    if (l_notf)  atomicOr(&notf01, 1);
    if (a[1] | a[3]) atomicOr(&odd_nz, 1);
    __syncthreads();
    if (threadIdx.x == 0) {
        int f;
        if (!not01)        f = odd_nz ? 1 : 2;
        else if (!notf01)  f = 3;
        else               f = 0;
        *flag = f;
    }
}

__global__ void bias2_kernel(const float* __restrict__ W_enc,
                             const float* __restrict__ b_enc,
                             const float* __restrict__ up_b_dec,
                             int nup, float* __restrict__ bias2)
{
    const int g = blockIdx.x * 256 + threadIdx.x;
    if (g >= F_DIM) return;
    float s = b_enc[g];
    for (int d = 0; d < D_DIM; ++d) {
        float ub = 0.f;
        for (int i = 0; i < nup; ++i) ub += up_b_dec[i * D_DIM + d];
        s = __builtin_fmaf(ub, W_enc[(size_t)d * F_DIM + g], s);
    }
    bias2[g] = s;
}

// exact radix top-k (ties -> lowest index), relu, sparse decode
__global__ __launch_bounds__(256)
void topk_decode_kernel(const float* __restrict__ approx,
                        const float* __restrict__ W_dec,
                        const float* __restrict__ b_dec,
                        const int* __restrict__ kptr,
                        float* __restrict__ out)
{
    __shared__ unsigned keys[F_DIM];
    __shared__ int hist[256];
    __shared__ unsigned sh_prefix;
    __shared__ int sh_need;
    __shared__ int sel_cnt, eq_cnt;
    __shared__ int sidx[128];
    __shared__ float sval[128];
    __shared__ int eqidx[1024];

    const int tid = threadIdx.x;
    const int row = blockIdx.x;
    const int k = *kptr;
    const float* arow = approx + (size_t)row * F_DIM;

    for (int j = tid; j < F_DIM; j += 256) {
        unsigned u = __float_as_uint(arow[j]);
        u = (u & 0x80000000u) ? ~u : (u | 0x80000000u);
        keys[j] = u;
    }
    if (tid == 0) { sh_prefix = 0u; sh_need = k; sel_cnt = 0; eq_cnt = 0; }
    __syncthreads();

    for (int shift = 24; shift >= 0; shift -= 8) {
        if (tid < 256) hist[tid] = 0;
        __syncthreads();
        const unsigned pfx = sh_prefix;
        for (int j = tid; j < F_DIM; j += 256) {
            const unsigned u = keys[j];
            const bool match =
                (shift == 24) || ((u >> (shift + 8)) == (pfx >> (shift + 8)));
            if (match) atomicAdd(&hist[(u >> shift) & 255], 1);
        }
        __syncthreads();
        if (tid == 0) {
            int need = sh_need;
            for (int b = 255; b >= 0; --b) {
                const int c = hist[b];
                if (c >= need) {
                    sh_prefix = pfx | ((unsigned)b << shift);
                    sh_need = need;
                    break;
                }
                need -= c;
            }
        }
        __syncthreads();
    }
    const unsigned T = sh_prefix;
    const int r = sh_need;

    for (int j = tid; j < F_DIM; j += 256) {
        const unsigned u = keys[j];
        if (u > T) {
            const int p = atomicAdd(&sel_cnt, 1);
            sidx[p] = j;
        } else if (u == T) {
            const int p = atomicAdd(&eq_cnt, 1);
            if (p < 1024) eqidx[p] = j;
        }
    }
    __syncthreads();

    if (tid == 0) {
        const int m = sel_cnt;
        const int e = eq_cnt < 1024 ? eq_cnt : 1024;
        for (int t2 = 0; t2 < r; ++t2) {
            int best = 0x7FFFFFFF, bi = -1;
            for (int q = 0; q < e; ++q) {
                const int v = eqidx[q];
                if (v >= 0 && v < best) { best = v; bi = q; }
            }
            if (bi >= 0) { eqidx[bi] = -1; sidx[m + t2] = best; }
        }
        sel_cnt = m + r;
        const int n = sel_cnt;
        for (int a2 = 1; a2 < n; ++a2) {
            const int v = sidx[a2];
            int b2 = a2 - 1;
            while (b2 >= 0 && sidx[b2] > v) { sidx[b2 + 1] = sidx[b2]; --b2; }
            sidx[b2 + 1] = v;
        }
    }
    __syncthreads();

    const int total = sel_cnt;
    for (int j = tid; j < total; j += 256) {
        const float v = arow[sidx[j]];
        sval[j] = v > 0.f ? v : 0.f;
    }
    __syncthreads();

    float acc0 = b_dec[tid];
    float acc1 = b_dec[tid + 256];
    float acc2 = b_dec[tid + 512];
    for (int j = 0; j < total; ++j) {
        const float v = sval[j];
        const float* wv = W_dec + (size_t)sidx[j] * D_DIM;
        acc0 = __builtin_fmaf(v, wv[tid],       acc0);
        acc1 = __builtin_fmaf(v, wv[tid + 256], acc1);
        acc2 = __builtin_fmaf(v, wv[tid + 512], acc2);
    }
    float* orow = out + (size_t)row * D_DIM;
    orow[tid] = acc0;
    orow[tid + 256] = acc1;
    orow[tid + 512] = acc2;
}

extern "C" void kernel_launch(void* const* d_in, const int* in_sizes, int n_in,
                              void* d_out, int out_size, void* d_ws, size_t ws_size,
                              hipStream_t stream)
{
    const float* x         = (const float*)d_in[1];
    const float* up_feats  = (const float*)d_in[2];
    const float* W_enc     = (const float*)d_in[3];
    const float* b_enc     = (const float*)d_in[4];
    const float* W_dec     = (const float*)d_in[5];
    const float* b_dec     = (const float*)d_in[6];
    const float* up_W_dec  = (const float*)d_in[7];
    const float* up_b_dec  = (const float*)d_in[8];
    const unsigned char* conn = (const unsigned char*)d_in[9];
    const int* kptr        = (const int*)d_in[10];

    const int BS  = in_sizes[1] / D_DIM;    // 2048
    const int NUP = in_sizes[8] / D_DIM;    // 3

    char* ws = (char*)d_ws;
    size_t off = 0;
    auto alloc = [&](size_t bytes) -> char* {
        off = (off + 255) & ~(size_t)255;
        char* p = ws + off; off += bytes; return p;
    };
    float* approx = (float*)alloc((size_t)BS * F_DIM * 4);
    float* bias2  = (float*)alloc(F_DIM * 4);
    int*   flag   = (int*)alloc(256);
    // packed arrays: logical n elems -> 2n f16 = 4n bytes
    f16* xp   = (f16*)alloc((size_t)BS * D_DIM * 4);
    f16* Wtp  = (f16*)alloc((size_t)F_DIM * D_DIM * 4);
    f16* uwdp = (f16*)alloc((size_t)NUP * F_DIM * D_DIM * 4);
    f16* ufp  = (f16*)alloc((size_t)NUP * BS * F_DIM * 4);

    off = (off + 255) & ~(size_t)255;
    const size_t rem = (ws_size > off) ? ws_size - off : 0;
    int FC = 4096;   // L3-resident vp chunk (134MB) + exactly-filling G2 grid
    while (FC > 128 && (size_t)FC * F_DIM * 4 > rem) FC >>= 1;
    f16* vp = (f16*)alloc((size_t)FC * F_DIM * 4);

    detect_kernel<<<1, 256, 0, stream>>>((const int*)conn, flag);
    bias2_kernel<<<F_DIM / 256, 256, 0, stream>>>(W_enc, b_enc, up_b_dec, NUP, bias2);

    split_kernel<<<(unsigned)((size_t)BS * D_DIM / 2048), 256, 0, stream>>>(
        x, xp, (size_t)BS * D_DIM, D_DIM);
    split_kernel<<<(unsigned)((size_t)NUP * F_DIM * D_DIM / 2048), 256, 0, stream>>>(
        up_W_dec, uwdp, (size_t)NUP * F_DIM * D_DIM, D_DIM);
    split_kernel<<<(unsigned)((size_t)NUP * BS * F_DIM / 2048), 256, 0, stream>>>(
        up_feats, ufp, (size_t)NUP * BS * F_DIM, F_DIM);
    transpose_split_kernel<<<F_DIM / 256, 256, 0, stream>>>(W_enc, Wtp);

    // G0: approx = x @ W_enc + bias2
    mfma_gemm<0><<<dim3(F_DIM / BMN, BS / BMN), 256, 0, stream>>>(
        xp, Wtp, approx, F_DIM, nullptr, bias2,
        nullptr, 0, flag, D_DIM, 0);

    for (int i = 0; i < NUP; ++i) {
        for (int fc = 0; fc < F_DIM; fc += FC) {
            const int chunk = (F_DIM - fc) < FC ? (F_DIM - fc) : FC;
            // G1: virtT[fd in chunk][fu] = (W_encT @ up_W_dec[i]^T) * maskT
            mfma_gemm<1><<<dim3(F_DIM / BMN, chunk / BMN), 256, 0, stream>>>(
                Wtp + (size_t)fc * (2 * D_DIM),
                uwdp + (size_t)i * F_DIM * (2 * D_DIM),
                nullptr, 0, vp, nullptr,
                conn, i, flag, D_DIM, fc);
            // G2: approx[:, fc:fc+chunk] += up_feats[i] @ virt  (K = 8192 fu)
            mfma_gemm<2><<<dim3(chunk / BMN, BS / BMN), 256, 0, stream>>>(
                ufp + (size_t)i * BS * (2 * F_DIM),
                vp,
                approx + fc, F_DIM, nullptr, nullptr,
                nullptr, 0, flag, F_DIM, 0);
        }
    }

    topk_decode_kernel<<<BS, 256, 0, stream>>>(
        approx, W_dec, b_dec, kptr, (float*)d_out);
}

// Round 8
// 4055.907 us; speedup vs baseline: 1.1482x; 1.1482x over previous
//
#include <hip/hip_runtime.h>
#include <hip/hip_bf16.h>

// SCAE forward on MI355X — f16 split-MFMA (Ootomo 3-product) pipeline.
//   v = h + l/2048 (f16 h,l; subnormal-guarded)  =>
//   A@B = Ah@Bh + (Ah@Bl + Al@Bh)/2048   (drop 2^-22 term)
// All GEMMs are A[M][K] x BT[N][K] row-major:
//   G0: approx = x @ W_enc       A=x_pk,   BT=W_encT_pk,   C=f32 +bias2
//   G1: virtT  = W_encT @ uWdT   A=Wt_pk,  BT=up_W_dec_pk, C=packed f16, mask in epilogue
//   G2: approx+= up_feats @ virt A=uf_pk,  BT=virtT_pk,    C=f32 +=
// Then exact radix top-k (ties->lowest index), relu, sparse decode.
//
// R8 = R6 revert (32x32 had inherent 4-way LDS bank conflicts; FC-split
// doubled A traffic) + three changes:
//  - STAGE(next) at the earliest legal point (right after the barrier) ->
//    full-step VMEM completion window
//  - l-fragment reads threaded INTO the MFMA stream (counted lgkmcnt
//    overlaps LDS pipe (~1500cyc/step/CU) with MFMA pipe (~1860cyc/step/CU)
//    instead of lockstep-serializing them)
//  - bijective XCD-chunked blockIdx swizzle (all grids % 8 == 0)

#define D_DIM 768
#define F_DIM 8192

typedef _Float16 f16;
typedef _Float16 f16x8 __attribute__((ext_vector_type(8)));
typedef float f32x4 __attribute__((ext_vector_type(4)));

#define BMN 128
#define BUFB 32768    // one K-tile: A 16KB + B 16KB (128 rows x 128B each)
#define PLNB 16384    // per-matrix region: 128 rows x 128B ([h|l] packed, XOR-8 swizzled)

__device__ inline void split_f32(float v, f16& h, f16& l) {
    float hf = (float)(f16)v;
    if (__builtin_fabsf(hf) < 6.1035156e-5f) hf = 0.f;   // keep h MFMA-normal
    h = (f16)hf;
    l = (f16)((v - hf) * 2048.0f);
}

// MODE 0: C = comb + bias[col]             (f32)
// MODE 1: Vp = packed_split(comb * mask)   (f16, row = 2*F_DIM elems)
// MODE 2: C += comb                        (f32)
template<int MODE>
__global__ __launch_bounds__(256, 2)
void mfma_gemm(const f16* __restrict__ Ap,     // packed, row stride 2K f16
               const f16* __restrict__ Bp,     // packed BT, row stride 2K f16
               float* __restrict__ C, int ldc,
               f16* __restrict__ Vp,
               const float* __restrict__ bias,
               const unsigned char* __restrict__ conn, int upIdx,
               const int* __restrict__ flagp,
               int K, int fdBase)
{
    __shared__ char lds[2 * BUFB];   // double-buffered K-tile
    const int tid = threadIdx.x;

    // bijective XCD-chunked swizzle (nwg always a multiple of 8 here)
    const unsigned gx = gridDim.x;
    const unsigned nwg = gx * gridDim.y;
    const unsigned bid0 = blockIdx.y * gx + blockIdx.x;
    const unsigned cpx = nwg >> 3;
    const unsigned bid = (bid0 & 7u) * cpx + (bid0 >> 3);
    const int bm = (int)(bid / gx) * BMN;
    const int bn = (int)(bid % gx) * BMN;

    const int w  = tid >> 6;
    const int l  = tid & 63;
    const int wr = (w >> 1) * 64;   // wave row origin
    const int wc = (w & 1) * 64;    // wave col origin

    // Staging: 2048 chunks of 16B per K-tile, 8/thread (c = tid + 256j).
    // chunk c: matrix p=c>>10 (0=A,1=B), row r=(c>>3)&127, phys slot sp=c&7.
    // logical slot = sp ^ (r&7) (XOR-8, involution); row source bytes are
    // CONTIGUOUS 128B = [h k-slots 0..3 | l k-slots 4..7]. LDS dest linear.
    const char* gsrc[8];
    #pragma unroll
    for (int j = 0; j < 8; ++j) {
        const int c = tid + 256 * j;
        const int p = c >> 10;
        const int q = c & 1023;
        const int r = q >> 3;
        const int sp = q & 7;
        const int slog = sp ^ (r & 7);
        const f16* base = p ? Bp : Ap;
        const int row0 = p ? bn : bm;
        gsrc[j] = (const char*)base + (size_t)(row0 + r) * ((size_t)K * 4)
                  + slog * 16;
    }

    #define STAGE(BUFSEL)                                                     \
        _Pragma("unroll")                                                     \
        for (int j = 0; j < 8; ++j) {                                         \
            __builtin_amdgcn_global_load_lds(                                 \
                (const __attribute__((address_space(1))) void*)gsrc[j],       \
                (__attribute__((address_space(3))) void*)                     \
                    (lds + (BUFSEL) * BUFB + (tid + 256 * j) * 16),           \
                16, 0, 0);                                                    \
            gsrc[j] += 128;   /* next 32-k packed block */                    \
        }

    f32x4 accH[4][4], accM[4][4];
    const f32x4 zero = {0.f, 0.f, 0.f, 0.f};
    #pragma unroll
    for (int a = 0; a < 4; ++a)
        #pragma unroll
        for (int b = 0; b < 4; ++b) { accH[a][b] = zero; accM[a][b] = zero; }

    const int steps = K >> 5;
    const int fr = l & 15;
    const int ks = l >> 4;          // k-slot 0..3

    // Hoisted loop-invariant LDS read byte-offsets (XOR-swizzle math ONCE).
    int offAH[4], offBH[4], offAL[4], offBL[4];
    #pragma unroll
    for (int f = 0; f < 4; ++f) {
        const int ra = wr + f * 16 + fr;
        const int rb = wc + f * 16 + fr;
        offAH[f] = ra * 128 + ((ks ^ (ra & 7)) * 16);
        offAL[f] = ra * 128 + (((4 + ks) ^ (ra & 7)) * 16);
        offBH[f] = PLNB + rb * 128 + ((ks ^ (rb & 7)) * 16);
        offBL[f] = PLNB + rb * 128 + (((4 + ks) ^ (rb & 7)) * 16);
    }

    STAGE(0);
    int cur = 0;
    for (int t = 0; t < steps; ++t) {
        // buf[cur]'s loads were issued one full step ago (hidden under MFMAs)
        asm volatile("s_waitcnt vmcnt(0)" ::: "memory");
        __syncthreads();

        // earliest legal STAGE point: buf[cur^1] was last read before the
        // barrier we just passed -> maximal in-flight window
        if (t + 1 < steps) STAGE(cur ^ 1);

        const char* Lb = lds + cur * BUFB;
        // ---- h-fragment reads (8) ----
        f16x8 ah[4], bh[4];
        #pragma unroll
        for (int mf = 0; mf < 4; ++mf) ah[mf] = *(const f16x8*)(Lb + offAH[mf]);
        #pragma unroll
        for (int nf = 0; nf < 4; ++nf) bh[nf] = *(const f16x8*)(Lb + offBH[nf]);

        __builtin_amdgcn_s_setprio(1);
        // ---- H phase part 1: nf=0,1 (8 MFMAs) ----
        #pragma unroll
        for (int nf = 0; nf < 2; ++nf)
            #pragma unroll
            for (int mf = 0; mf < 4; ++mf)
                accH[mf][nf] = __builtin_amdgcn_mfma_f32_16x16x32_f16(
                    ah[mf], bh[nf], accH[mf][nf], 0, 0, 0);

        // ---- bl reads (4) overlap H part 2 ----
        f16x8 bl[4];
        #pragma unroll
        for (int nf = 0; nf < 4; ++nf) bl[nf] = *(const f16x8*)(Lb + offBL[nf]);

        // ---- H phase part 2: nf=2,3 (8 MFMAs) ----
        #pragma unroll
        for (int nf = 2; nf < 4; ++nf)
            #pragma unroll
            for (int mf = 0; mf < 4; ++mf)
                accH[mf][nf] = __builtin_amdgcn_mfma_f32_16x16x32_f16(
                    ah[mf], bh[nf], accH[mf][nf], 0, 0, 0);

        // ---- al reads (4) overlap first M MFMAs ----
        f16x8 al[4];
        #pragma unroll
        for (int mf = 0; mf < 4; ++mf) al[mf] = *(const f16x8*)(Lb + offAL[mf]);

        // ---- M phase: ah x bl (16 MFMAs) ----
        #pragma unroll
        for (int nf = 0; nf < 4; ++nf)
            #pragma unroll
            for (int mf = 0; mf < 4; ++mf)
                accM[mf][nf] = __builtin_amdgcn_mfma_f32_16x16x32_f16(
                    ah[mf], bl[nf], accM[mf][nf], 0, 0, 0);
        // ---- M phase: al x bh (16 MFMAs) ----
        #pragma unroll
        for (int mf = 0; mf < 4; ++mf)
            #pragma unroll
            for (int nf = 0; nf < 4; ++nf)
                accM[mf][nf] = __builtin_amdgcn_mfma_f32_16x16x32_f16(
                    al[mf], bh[nf], accM[mf][nf], 0, 0, 0);
        __builtin_amdgcn_s_setprio(0);

        cur ^= 1;
    }
    #undef STAGE

    const float MS = 4.8828125e-4f;   // 1/2048
    const int flag = (MODE == 1) ? *flagp : 0;

    #pragma unroll
    for (int mf = 0; mf < 4; ++mf) {
        const int row0 = wr + mf * 16 + (l >> 4) * 4;   // local row of reg 0
        #pragma unroll
        for (int nf = 0; nf < 4; ++nf) {
            const int col = wc + nf * 16 + (l & 15);
            float v[4];
            #pragma unroll
            for (int rr = 0; rr < 4; ++rr)
                v[rr] = accH[mf][nf][rr] + accM[mf][nf][rr] * MS;

            if (MODE == 0) {
                const float bb = bias[bn + col];
                #pragma unroll
                for (int rr = 0; rr < 4; ++rr)
                    C[(size_t)(bm + row0 + rr) * ldc + (bn + col)] = v[rr] + bb;
            } else if (MODE == 2) {
                #pragma unroll
                for (int rr = 0; rr < 4; ++rr) {
                    float* cp = &C[(size_t)(bm + row0 + rr) * ldc + (bn + col)];
                    *cp = *cp + v[rr];
                }
            } else {
                const size_t fu = (size_t)(bn + col);
                const size_t fd0 = (size_t)(fdBase + bm + row0);
                int m[4];
                if (flag == 1) {
                    const int4 mm = *(const int4*)((const int*)conn +
                        (size_t)upIdx * F_DIM * F_DIM + fu * F_DIM + fd0);
                    m[0] = mm.x; m[1] = mm.y; m[2] = mm.z; m[3] = mm.w;
                } else if (flag == 0) {
                    const uchar4 mm = *(const uchar4*)(conn +
                        (size_t)upIdx * F_DIM * F_DIM + fu * F_DIM + fd0);
                    m[0] = mm.x; m[1] = mm.y; m[2] = mm.z; m[3] = mm.w;
                } else if (flag == 2) {
                    const long long* pp = (const long long*)conn +
                        (size_t)upIdx * F_DIM * F_DIM + fu * F_DIM + fd0;
                    m[0] = (int)pp[0]; m[1] = (int)pp[1];
                    m[2] = (int)pp[2]; m[3] = (int)pp[3];
                } else {
                    const float4 mm = *(const float4*)((const float*)conn +
                        (size_t)upIdx * F_DIM * F_DIM + fu * F_DIM + fd0);
                    m[0] = mm.x != 0.f; m[1] = mm.y != 0.f;
                    m[2] = mm.z != 0.f; m[3] = mm.w != 0.f;
                }
                // packed write: row fd, k=fu -> fd*2F + (fu>>5)*64 + (fu&31)
                const size_t kblk = (fu >> 5) * 64 + (fu & 31);
                #pragma unroll
                for (int rr = 0; rr < 4; ++rr) {
                    const float vv = m[rr] ? v[rr] : 0.f;
                    f16 hh, ll;
                    split_f32(vv, hh, ll);
                    const size_t o = (size_t)(bm + row0 + rr) * (2 * F_DIM) + kblk;
                    Vp[o] = hh; Vp[o + 32] = ll;
                }
            }
        }
    }
}

// elementwise split into packed layout: row r of K -> 2K f16, blocks of
// [32 h | 32 l]. 8 contiguous k per thread (stay within one 32-block).
__global__ __launch_bounds__(256)
void split_kernel(const float* __restrict__ src, f16* __restrict__ dst,
                  size_t n, int K)
{
    const size_t e = ((size_t)blockIdx.x * 256 + threadIdx.x) * 8;
    if (e >= n) return;
    const size_t r = e / (size_t)K;
    const int k = (int)(e - r * (size_t)K);
    const float4 a = *(const float4*)(src + e);
    const float4 b = *(const float4*)(src + e + 4);
    f16 hv[8], lv[8];
    const float s[8] = {a.x, a.y, a.z, a.w, b.x, b.y, b.z, b.w};
    #pragma unroll
    for (int i = 0; i < 8; ++i) split_f32(s[i], hv[i], lv[i]);
    const size_t base = r * (size_t)(2 * K) + (size_t)((k >> 5) * 64 + (k & 31));
    *(f16x8*)(dst + base)      = *(const f16x8*)hv;
    *(f16x8*)(dst + base + 32) = *(const f16x8*)lv;
}

// W_enc [768][8192] -> packed W_encT rows f (K=768); reads coalesced along f
__global__ __launch_bounds__(256)
void transpose_split_kernel(const float* __restrict__ W, f16* __restrict__ dst)
{
    const int f = blockIdx.x * 256 + threadIdx.x;
    for (int dc = 0; dc < D_DIM / 8; ++dc) {
        const int k = dc * 8;
        f16 hv[8], lv[8];
        #pragma unroll
        for (int j = 0; j < 8; ++j)
            split_f32(W[(size_t)(k + j) * F_DIM + f], hv[j], lv[j]);
        const size_t base = (size_t)f * (2 * D_DIM) + (k >> 5) * 64 + (k & 31);
        *(f16x8*)(dst + base)      = *(const f16x8*)hv;
        *(f16x8*)(dst + base + 32) = *(const f16x8*)lv;
    }
}

// conn_mask storage-layout detection: 0=u8, 1=i32, 2=i64, 3=f32
__global__ void detect_kernel(const int* __restrict__ conn, int* __restrict__ flag)
{
    __shared__ int not01, notf01, odd_nz;
    if (threadIdx.x == 0) { not01 = 0; notf01 = 0; odd_nz = 0; }
    __syncthreads();
    const int4 v = ((const int4*)conn)[threadIdx.x];
    const unsigned a[4] = {(unsigned)v.x, (unsigned)v.y,
                           (unsigned)v.z, (unsigned)v.w};
    int l_not01 = 0, l_notf = 0;
    #pragma unroll
    for (int i = 0; i < 4; ++i) {
        if (a[i] > 1u) l_not01 = 1;
        if (a[i] != 0u && a[i] != 0x3F800000u) l_notf = 1;
    }
    if (l_not01) atomicOr(&not01, 1);
    if (l_notf)  atomicOr(&notf01, 1);
    if (a[1] | a[3]) atomicOr(&odd_nz, 1);
    __syncthreads();
    if (threadIdx.x == 0) {
        int f;
        if (!not01)        f = odd_nz ? 1 : 2;
        else if (!notf01)  f = 3;
        else               f = 0;
        *flag = f;
    }
}

__global__ void bias2_kernel(const float* __restrict__ W_enc,
                             const float* __restrict__ b_enc,
                             const float* __restrict__ up_b_dec,
                             int nup, float* __restrict__ bias2)
{
    const int g = blockIdx.x * 256 + threadIdx.x;
    if (g >= F_DIM) return;
    float s = b_enc[g];
    for (int d = 0; d < D_DIM; ++d) {
        float ub = 0.f;
        for (int i = 0; i < nup; ++i) ub += up_b_dec[i * D_DIM + d];
        s = __builtin_fmaf(ub, W_enc[(size_t)d * F_DIM + g], s);
    }
    bias2[g] = s;
}

// exact radix top-k (ties -> lowest index), relu, sparse decode
__global__ __launch_bounds__(256)
void topk_decode_kernel(const float* __restrict__ approx,
                        const float* __restrict__ W_dec,
                        const float* __restrict__ b_dec,
                        const int* __restrict__ kptr,
                        float* __restrict__ out)
{
    __shared__ unsigned keys[F_DIM];
    __shared__ int hist[256];
    __shared__ unsigned sh_prefix;
    __shared__ int sh_need;
    __shared__ int sel_cnt, eq_cnt;
    __shared__ int sidx[128];
    __shared__ float sval[128];
    __shared__ int eqidx[1024];

    const int tid = threadIdx.x;
    const int row = blockIdx.x;
    const int k = *kptr;
    const float* arow = approx + (size_t)row * F_DIM;

    for (int j = tid; j < F_DIM; j += 256) {
        unsigned u = __float_as_uint(arow[j]);
        u = (u & 0x80000000u) ? ~u : (u | 0x80000000u);
        keys[j] = u;
    }
    if (tid == 0) { sh_prefix = 0u; sh_need = k; sel_cnt = 0; eq_cnt = 0; }
    __syncthreads();

    for (int shift = 24; shift >= 0; shift -= 8) {
        if (tid < 256) hist[tid] = 0;
        __syncthreads();
        const unsigned pfx = sh_prefix;
        for (int j = tid; j < F_DIM; j += 256) {
            const unsigned u = keys[j];
            const bool match =
                (shift == 24) || ((u >> (shift + 8)) == (pfx >> (shift + 8)));
            if (match) atomicAdd(&hist[(u >> shift) & 255], 1);
        }
        __syncthreads();
        if (tid == 0) {
            int need = sh_need;
            for (int b = 255; b >= 0; --b) {
                const int c = hist[b];
                if (c >= need) {
                    sh_prefix = pfx | ((unsigned)b << shift);
                    sh_need = need;
                    break;
                }
                need -= c;
            }
        }
        __syncthreads();
    }
    const unsigned T = sh_prefix;
    const int r = sh_need;

    for (int j = tid; j < F_DIM; j += 256) {
        const unsigned u = keys[j];
        if (u > T) {
            const int p = atomicAdd(&sel_cnt, 1);
            sidx[p] = j;
        } else if (u == T) {
            const int p = atomicAdd(&eq_cnt, 1);
            if (p < 1024) eqidx[p] = j;
        }
    }
    __syncthreads();

    if (tid == 0) {
        const int m = sel_cnt;
        const int e = eq_cnt < 1024 ? eq_cnt : 1024;
        for (int t2 = 0; t2 < r; ++t2) {
            int best = 0x7FFFFFFF, bi = -1;
            for (int q = 0; q < e; ++q) {
                const int v = eqidx[q];
                if (v >= 0 && v < best) { best = v; bi = q; }
            }
            if (bi >= 0) { eqidx[bi] = -1; sidx[m + t2] = best; }
        }
        sel_cnt = m + r;
        const int n = sel_cnt;
        for (int a2 = 1; a2 < n; ++a2) {
            const int v = sidx[a2];
            int b2 = a2 - 1;
            while (b2 >= 0 && sidx[b2] > v) { sidx[b2 + 1] = sidx[b2]; --b2; }
            sidx[b2 + 1] = v;
        }
    }
    __syncthreads();

    const int total = sel_cnt;
    for (int j = tid; j < total; j += 256) {
        const float v = arow[sidx[j]];
        sval[j] = v > 0.f ? v : 0.f;
    }
    __syncthreads();

    float acc0 = b_dec[tid];
    float acc1 = b_dec[tid + 256];
    float acc2 = b_dec[tid + 512];
    for (int j = 0; j < total; ++j) {
        const float v = sval[j];
        const float* wv = W_dec + (size_t)sidx[j] * D_DIM;
        acc0 = __builtin_fmaf(v, wv[tid],       acc0);
        acc1 = __builtin_fmaf(v, wv[tid + 256], acc1);
        acc2 = __builtin_fmaf(v, wv[tid + 512], acc2);
    }
    float* orow = out + (size_t)row * D_DIM;
    orow[tid] = acc0;
    orow[tid + 256] = acc1;
    orow[tid + 512] = acc2;
}

extern "C" void kernel_launch(void* const* d_in, const int* in_sizes, int n_in,
                              void* d_out, int out_size, void* d_ws, size_t ws_size,
                              hipStream_t stream)
{
    const float* x         = (const float*)d_in[1];
    const float* up_feats  = (const float*)d_in[2];
    const float* W_enc     = (const float*)d_in[3];
    const float* b_enc     = (const float*)d_in[4];
    const float* W_dec     = (const float*)d_in[5];
    const float* b_dec     = (const float*)d_in[6];
    const float* up_W_dec  = (const float*)d_in[7];
    const float* up_b_dec  = (const float*)d_in[8];
    const unsigned char* conn = (const unsigned char*)d_in[9];
    const int* kptr        = (const int*)d_in[10];

    const int BS  = in_sizes[1] / D_DIM;    // 2048
    const int NUP = in_sizes[8] / D_DIM;    // 3

    char* ws = (char*)d_ws;
    size_t off = 0;
    auto alloc = [&](size_t bytes) -> char* {
        off = (off + 255) & ~(size_t)255;
        char* p = ws + off; off += bytes; return p;
    };
    float* approx = (float*)alloc((size_t)BS * F_DIM * 4);
    float* bias2  = (float*)alloc(F_DIM * 4);
    int*   flag   = (int*)alloc(256);
    // packed arrays: logical n elems -> 2n f16 = 4n bytes
    f16* xp   = (f16*)alloc((size_t)BS * D_DIM * 4);
    f16* Wtp  = (f16*)alloc((size_t)F_DIM * D_DIM * 4);
    f16* uwdp = (f16*)alloc((size_t)NUP * F_DIM * D_DIM * 4);
    f16* ufp  = (f16*)alloc((size_t)NUP * BS * F_DIM * 4);

    off = (off + 255) & ~(size_t)255;
    const size_t rem = (ws_size > off) ? ws_size - off : 0;
    int FC = (int)((rem / ((size_t)F_DIM * 4)) / 128 * 128);
    if (FC > F_DIM) FC = F_DIM;
    if (FC < 128) FC = 128;   // ws observed ~3.2GB -> FC = 8192
    f16* vp = (f16*)alloc((size_t)FC * F_DIM * 4);

    detect_kernel<<<1, 256, 0, stream>>>((const int*)conn, flag);
    bias2_kernel<<<F_DIM / 256, 256, 0, stream>>>(W_enc, b_enc, up_b_dec, NUP, bias2);

    split_kernel<<<(unsigned)((size_t)BS * D_DIM / 2048), 256, 0, stream>>>(
        x, xp, (size_t)BS * D_DIM, D_DIM);
    split_kernel<<<(unsigned)((size_t)NUP * F_DIM * D_DIM / 2048), 256, 0, stream>>>(
        up_W_dec, uwdp, (size_t)NUP * F_DIM * D_DIM, D_DIM);
    split_kernel<<<(unsigned)((size_t)NUP * BS * F_DIM / 2048), 256, 0, stream>>>(
        up_feats, ufp, (size_t)NUP * BS * F_DIM, F_DIM);
    transpose_split_kernel<<<F_DIM / 256, 256, 0, stream>>>(W_enc, Wtp);

    // G0: approx = x @ W_enc + bias2
    mfma_gemm<0><<<dim3(F_DIM / BMN, BS / BMN), 256, 0, stream>>>(
        xp, Wtp, approx, F_DIM, nullptr, bias2,
        nullptr, 0, flag, D_DIM, 0);

    for (int i = 0; i < NUP; ++i) {
        for (int fc = 0; fc < F_DIM; fc += FC) {
            const int chunk = (F_DIM - fc) < FC ? (F_DIM - fc) : FC;
            // G1: virtT[fd in chunk][fu] = (W_encT @ up_W_dec[i]^T) * maskT
            mfma_gemm<1><<<dim3(F_DIM / BMN, chunk / BMN), 256, 0, stream>>>(
                Wtp + (size_t)fc * (2 * D_DIM),
                uwdp + (size_t)i * F_DIM * (2 * D_DIM),
                nullptr, 0, vp, nullptr,
                conn, i, flag, D_DIM, fc);
            // G2: approx[:, fc:fc+chunk] += up_feats[i] @ virt  (K = 8192 fu)
            mfma_gemm<2><<<dim3(chunk / BMN, BS / BMN), 256, 0, stream>>>(
                ufp + (size_t)i * BS * (2 * F_DIM),
                vp,
                approx + fc, F_DIM, nullptr, nullptr,
                nullptr, 0, flag, F_DIM, 0);
        }
    }

    topk_decode_kernel<<<BS, 256, 0, stream>>>(
        approx, W_dec, b_dec, kptr, (float*)d_out);
}

// Round 9
// 3996.757 us; speedup vs baseline: 1.1652x; 1.0148x over previous
//
#include <hip/hip_runtime.h>
#include <hip/hip_bf16.h>

// SCAE forward on MI355X — f16 split-MFMA (Ootomo 3-product) pipeline.
//   v = h + l/2048 (f16 h,l; subnormal-guarded)  =>
//   A@B = Ah@Bh + (Ah@Bl + Al@Bh)/2048   (drop 2^-22 term)
// All GEMMs are A[M][K] x BT[N][K] row-major:
//   G0: approx = x @ W_enc       A=x_pk,   BT=W_encT_pk,   C=f32 +bias2
//   G1: virtT  = W_encT @ uWdT   A=Wt_pk,  BT=up_W_dec_pk, C=packed f16, mask in epilogue
//   G2: approx+= up_feats @ virt A=uf_pk,  BT=virtT_pk,    C=f32 +=
// Then exact radix top-k (ties->lowest index), relu, sparse decode.
//
// R9 (vs R8): XCD swizzle REVERTED (R8 counters: it anti-correlated block
// placement -> G2 FETCH doubled 1.1->2.2GB, the whole regression).
// NEW: NT column-strips per block (template). G2 uses NT=2 -> grid 512 =
// ONE co-resident generation; vp (268MB) is fetched once (compulsory),
// killing the generation-2 re-read that made R6 fetch 1.1GB.

#define D_DIM 768
#define F_DIM 8192

typedef _Float16 f16;
typedef _Float16 f16x8 __attribute__((ext_vector_type(8)));
typedef float f32x4 __attribute__((ext_vector_type(4)));

#define BMN 128
#define BUFB 32768    // one K-tile: A 16KB + B 16KB (128 rows x 128B each)
#define PLNB 16384    // per-matrix region: 128 rows x 128B ([h|l] packed, XOR-8 swizzled)

__device__ inline void split_f32(float v, f16& h, f16& l) {
    float hf = (float)(f16)v;
    if (__builtin_fabsf(hf) < 6.1035156e-5f) hf = 0.f;   // keep h MFMA-normal
    h = (f16)hf;
    l = (f16)((v - hf) * 2048.0f);
}

// MODE 0: C = comb + bias[col]             (f32)
// MODE 1: Vp = packed_split(comb * mask)   (f16, row = 2*F_DIM elems)
// MODE 2: C += comb                        (f32)
template<int MODE, int NT>
__global__ __launch_bounds__(256, 2)
void mfma_gemm(const f16* __restrict__ Ap,     // packed, row stride 2K f16
               const f16* __restrict__ Bp,     // packed BT, row stride 2K f16
               float* __restrict__ C, int ldc,
               f16* __restrict__ Vp,
               const float* __restrict__ bias,
               const unsigned char* __restrict__ conn, int upIdx,
               const int* __restrict__ flagp,
               int K, int fdBase)
{
    __shared__ char lds[2 * BUFB];   // double-buffered K-tile
    const int tid = threadIdx.x;
    const int bm = blockIdx.y * BMN;
    const int bnBase = blockIdx.x * (BMN * NT);

    const int w  = tid >> 6;
    const int l  = tid & 63;
    const int wr = (w >> 1) * 64;   // wave row origin
    const int wc = (w & 1) * 64;    // wave col origin

    const int steps = K >> 5;
    const int fr = l & 15;
    const int ks = l >> 4;          // k-slot 0..3

    // Hoisted loop-invariant LDS read byte-offsets (XOR-swizzle math ONCE).
    int offAH[4], offBH[4], offAL[4], offBL[4];
    #pragma unroll
    for (int f = 0; f < 4; ++f) {
        const int ra = wr + f * 16 + fr;
        const int rb = wc + f * 16 + fr;
        offAH[f] = ra * 128 + ((ks ^ (ra & 7)) * 16);
        offAL[f] = ra * 128 + (((4 + ks) ^ (ra & 7)) * 16);
        offBH[f] = PLNB + rb * 128 + ((ks ^ (rb & 7)) * 16);
        offBL[f] = PLNB + rb * 128 + (((4 + ks) ^ (rb & 7)) * 16);
    }

    const float MS = 4.8828125e-4f;   // 1/2048
    const int flag = (MODE == 1) ? *flagp : 0;

    // Staging map per K-tile: 2048 chunks of 16B, 8/thread (c = tid + 256j).
    // chunk c: matrix p=c>>10 (0=A,1=B), row r=(c>>3)&127, phys slot sp=c&7.
    // logical slot = sp ^ (r&7) (XOR-8, involution); row source bytes are
    // CONTIGUOUS 128B = [h k-slots 0..3 | l k-slots 4..7]. LDS dest linear.
    int srow[8], sslot[8], sisB[8];
    #pragma unroll
    for (int j = 0; j < 8; ++j) {
        const int c = tid + 256 * j;
        const int q = c & 1023;
        const int r = q >> 3;
        sisB[j] = c >> 10;
        srow[j] = r;
        sslot[j] = (q & 7) ^ (r & 7);
    }

    #define STAGE(BUFSEL)                                                     \
        _Pragma("unroll")                                                     \
        for (int j = 0; j < 8; ++j) {                                         \
            __builtin_amdgcn_global_load_lds(                                 \
                (const __attribute__((address_space(1))) void*)gsrc[j],       \
                (__attribute__((address_space(3))) void*)                     \
                    (lds + (BUFSEL) * BUFB + (tid + 256 * j) * 16),           \
                16, 0, 0);                                                    \
            gsrc[j] += 128;   /* next 32-k packed block */                    \
        }

    for (int nt = 0; nt < NT; ++nt) {
        const int bn = bnBase + nt * BMN;

        const char* gsrc[8];
        #pragma unroll
        for (int j = 0; j < 8; ++j) {
            const f16* base = sisB[j] ? Bp : Ap;
            const int row0 = sisB[j] ? bn : bm;
            gsrc[j] = (const char*)base
                    + (size_t)(row0 + srow[j]) * ((size_t)K * 4) + sslot[j] * 16;
        }

        f32x4 accH[4][4], accM[4][4];
        const f32x4 zero = {0.f, 0.f, 0.f, 0.f};
        #pragma unroll
        for (int a = 0; a < 4; ++a)
            #pragma unroll
            for (int b = 0; b < 4; ++b) { accH[a][b] = zero; accM[a][b] = zero; }

        // all LDS reads of the previous nt completed (its K-loop barrier
        // chain); one barrier protects buf0 overwrite at nt > 0
        if (nt > 0) __syncthreads();
        STAGE(0);
        int cur = 0;
        for (int t = 0; t < steps; ++t) {
            // buf[cur]'s loads were issued one full step ago
            asm volatile("s_waitcnt vmcnt(0)" ::: "memory");
            __syncthreads();

            // earliest legal STAGE point -> maximal in-flight window
            if (t + 1 < steps) STAGE(cur ^ 1);

            const char* Lb = lds + cur * BUFB;
            // ---- h-fragment reads (8) ----
            f16x8 ah[4], bh[4];
            #pragma unroll
            for (int mf = 0; mf < 4; ++mf) ah[mf] = *(const f16x8*)(Lb + offAH[mf]);
            #pragma unroll
            for (int nf = 0; nf < 4; ++nf) bh[nf] = *(const f16x8*)(Lb + offBH[nf]);

            __builtin_amdgcn_s_setprio(1);
            // ---- H phase part 1: nf=0,1 ----
            #pragma unroll
            for (int nf = 0; nf < 2; ++nf)
                #pragma unroll
                for (int mf = 0; mf < 4; ++mf)
                    accH[mf][nf] = __builtin_amdgcn_mfma_f32_16x16x32_f16(
                        ah[mf], bh[nf], accH[mf][nf], 0, 0, 0);

            // ---- bl reads overlap H part 2 ----
            f16x8 bl[4];
            #pragma unroll
            for (int nf = 0; nf < 4; ++nf) bl[nf] = *(const f16x8*)(Lb + offBL[nf]);

            // ---- H phase part 2: nf=2,3 ----
            #pragma unroll
            for (int nf = 2; nf < 4; ++nf)
                #pragma unroll
                for (int mf = 0; mf < 4; ++mf)
                    accH[mf][nf] = __builtin_amdgcn_mfma_f32_16x16x32_f16(
                        ah[mf], bh[nf], accH[mf][nf], 0, 0, 0);

            // ---- al reads overlap first M MFMAs ----
            f16x8 al[4];
            #pragma unroll
            for (int mf = 0; mf < 4; ++mf) al[mf] = *(const f16x8*)(Lb + offAL[mf]);

            // ---- M phase: ah x bl ----
            #pragma unroll
            for (int nf = 0; nf < 4; ++nf)
                #pragma unroll
                for (int mf = 0; mf < 4; ++mf)
                    accM[mf][nf] = __builtin_amdgcn_mfma_f32_16x16x32_f16(
                        ah[mf], bl[nf], accM[mf][nf], 0, 0, 0);
            // ---- M phase: al x bh ----
            #pragma unroll
            for (int mf = 0; mf < 4; ++mf)
                #pragma unroll
                for (int nf = 0; nf < 4; ++nf)
                    accM[mf][nf] = __builtin_amdgcn_mfma_f32_16x16x32_f16(
                        al[mf], bh[nf], accM[mf][nf], 0, 0, 0);
            __builtin_amdgcn_s_setprio(0);

            cur ^= 1;
        }

        // ---- epilogue for this strip tile ----
        #pragma unroll
        for (int mf = 0; mf < 4; ++mf) {
            const int row0 = wr + mf * 16 + (l >> 4) * 4;   // local row of reg 0
            #pragma unroll
            for (int nf = 0; nf < 4; ++nf) {
                const int col = wc + nf * 16 + (l & 15);
                float v[4];
                #pragma unroll
                for (int rr = 0; rr < 4; ++rr)
                    v[rr] = accH[mf][nf][rr] + accM[mf][nf][rr] * MS;

                if (MODE == 0) {
                    const float bb = bias[bn + col];
                    #pragma unroll
                    for (int rr = 0; rr < 4; ++rr)
                        C[(size_t)(bm + row0 + rr) * ldc + (bn + col)] = v[rr] + bb;
                } else if (MODE == 2) {
                    #pragma unroll
                    for (int rr = 0; rr < 4; ++rr) {
                        float* cp = &C[(size_t)(bm + row0 + rr) * ldc + (bn + col)];
                        *cp = *cp + v[rr];
                    }
                } else {
                    const size_t fu = (size_t)(bn + col);
                    const size_t fd0 = (size_t)(fdBase + bm + row0);
                    int m[4];
                    if (flag == 1) {
                        const int4 mm = *(const int4*)((const int*)conn +
                            (size_t)upIdx * F_DIM * F_DIM + fu * F_DIM + fd0);
                        m[0] = mm.x; m[1] = mm.y; m[2] = mm.z; m[3] = mm.w;
                    } else if (flag == 0) {
                        const uchar4 mm = *(const uchar4*)(conn +
                            (size_t)upIdx * F_DIM * F_DIM + fu * F_DIM + fd0);
                        m[0] = mm.x; m[1] = mm.y; m[2] = mm.z; m[3] = mm.w;
                    } else if (flag == 2) {
                        const long long* pp = (const long long*)conn +
                            (size_t)upIdx * F_DIM * F_DIM + fu * F_DIM + fd0;
                        m[0] = (int)pp[0]; m[1] = (int)pp[1];
                        m[2] = (int)pp[2]; m[3] = (int)pp[3];
                    } else {
                        const float4 mm = *(const float4*)((const float*)conn +
                            (size_t)upIdx * F_DIM * F_DIM + fu * F_DIM + fd0);
                        m[0] = mm.x != 0.f; m[1] = mm.y != 0.f;
                        m[2] = mm.z != 0.f; m[3] = mm.w != 0.f;
                    }
                    // packed write: row fd, k=fu -> fd*2F + (fu>>5)*64 + (fu&31)
                    const size_t kblk = (fu >> 5) * 64 + (fu & 31);
                    #pragma unroll
                    for (int rr = 0; rr < 4; ++rr) {
                        const float vv = m[rr] ? v[rr] : 0.f;
                        f16 hh, ll;
                        split_f32(vv, hh, ll);
                        const size_t o = (size_t)(bm + row0 + rr) * (2 * F_DIM) + kblk;
                        Vp[o] = hh; Vp[o + 32] = ll;
                    }
                }
            }
        }
    }
    #undef STAGE
}

// elementwise split into packed layout: row r of K -> 2K f16, blocks of
// [32 h | 32 l]. 8 contiguous k per thread (stay within one 32-block).
__global__ __launch_bounds__(256)
void split_kernel(const float* __restrict__ src, f16* __restrict__ dst,
                  size_t n, int K)
{
    const size_t e = ((size_t)blockIdx.x * 256 + threadIdx.x) * 8;
    if (e >= n) return;
    const size_t r = e / (size_t)K;
    const int k = (int)(e - r * (size_t)K);
    const float4 a = *(const float4*)(src + e);
    const float4 b = *(const float4*)(src + e + 4);
    f16 hv[8], lv[8];
    const float s[8] = {a.x, a.y, a.z, a.w, b.x, b.y, b.z, b.w};
    #pragma unroll
    for (int i = 0; i < 8; ++i) split_f32(s[i], hv[i], lv[i]);
    const size_t base = r * (size_t)(2 * K) + (size_t)((k >> 5) * 64 + (k & 31));
    *(f16x8*)(dst + base)      = *(const f16x8*)hv;
    *(f16x8*)(dst + base + 32) = *(const f16x8*)lv;
}

// W_enc [768][8192] -> packed W_encT rows f (K=768); reads coalesced along f
__global__ __launch_bounds__(256)
void transpose_split_kernel(const float* __restrict__ W, f16* __restrict__ dst)
{
    const int f = blockIdx.x * 256 + threadIdx.x;
    for (int dc = 0; dc < D_DIM / 8; ++dc) {
        const int k = dc * 8;
        f16 hv[8], lv[8];
        #pragma unroll
        for (int j = 0; j < 8; ++j)
            split_f32(W[(size_t)(k + j) * F_DIM + f], hv[j], lv[j]);
        const size_t base = (size_t)f * (2 * D_DIM) + (k >> 5) * 64 + (k & 31);
        *(f16x8*)(dst + base)      = *(const f16x8*)hv;
        *(f16x8*)(dst + base + 32) = *(const f16x8*)lv;
    }
}

// conn_mask storage-layout detection: 0=u8, 1=i32, 2=i64, 3=f32
__global__ void detect_kernel(const int* __restrict__ conn, int* __restrict__ flag)
{
    __shared__ int not01, notf01, odd_nz;
    if (threadIdx.x == 0) { not01 = 0; notf01 = 0; odd_nz = 0; }
    __syncthreads();
    const int4 v = ((const int4*)conn)[threadIdx.x];
    const unsigned a[4] = {(unsigned)v.x, (unsigned)v.y,
                           (unsigned)v.z, (unsigned)v.w};
    int l_not01 = 0, l_notf = 0;
    #pragma unroll
    for (int i = 0; i < 4; ++i) {
        if (a[i] > 1u) l_not01 = 1;
        if (a[i] != 0u && a[i] != 0x3F800000u) l_notf = 1;
    }
    if (l_not01) atomicOr(&not01, 1);
    if (l_notf)  atomicOr(&notf01, 1);
    if (a[1] | a[3]) atomicOr(&odd_nz, 1);
    __syncthreads();
    if (threadIdx.x == 0) {
        int f;
        if (!not01)        f = odd_nz ? 1 : 2;
        else if (!notf01)  f = 3;
        else               f = 0;
        *flag = f;
    }
}

__global__ void bias2_kernel(const float* __restrict__ W_enc,
                             const float* __restrict__ b_enc,
                             const float* __restrict__ up_b_dec,
                             int nup, float* __restrict__ bias2)
{
    const int g = blockIdx.x * 256 + threadIdx.x;
    if (g >= F_DIM) return;
    float s = b_enc[g];
    for (int d = 0; d < D_DIM; ++d) {
        float ub = 0.f;
        for (int i = 0; i < nup; ++i) ub += up_b_dec[i * D_DIM + d];
        s = __builtin_fmaf(ub, W_enc[(size_t)d * F_DIM + g], s);
    }
    bias2[g] = s;
}

// exact radix top-k (ties -> lowest index), relu, sparse decode
__global__ __launch_bounds__(256)
void topk_decode_kernel(const float* __restrict__ approx,
                        const float* __restrict__ W_dec,
                        const float* __restrict__ b_dec,
                        const int* __restrict__ kptr,
                        float* __restrict__ out)
{
    __shared__ unsigned keys[F_DIM];
    __shared__ int hist[256];
    __shared__ unsigned sh_prefix;
    __shared__ int sh_need;
    __shared__ int sel_cnt, eq_cnt;
    __shared__ int sidx[128];
    __shared__ float sval[128];
    __shared__ int eqidx[1024];

    const int tid = threadIdx.x;
    const int row = blockIdx.x;
    const int k = *kptr;
    const float* arow = approx + (size_t)row * F_DIM;

    for (int j = tid; j < F_DIM; j += 256) {
        unsigned u = __float_as_uint(arow[j]);
        u = (u & 0x80000000u) ? ~u : (u | 0x80000000u);
        keys[j] = u;
    }
    if (tid == 0) { sh_prefix = 0u; sh_need = k; sel_cnt = 0; eq_cnt = 0; }
    __syncthreads();

    for (int shift = 24; shift >= 0; shift -= 8) {
        if (tid < 256) hist[tid] = 0;
        __syncthreads();
        const unsigned pfx = sh_prefix;
        for (int j = tid; j < F_DIM; j += 256) {
            const unsigned u = keys[j];
            const bool match =
                (shift == 24) || ((u >> (shift + 8)) == (pfx >> (shift + 8)));
            if (match) atomicAdd(&hist[(u >> shift) & 255], 1);
        }
        __syncthreads();
        if (tid == 0) {
            int need = sh_need;
            for (int b = 255; b >= 0; --b) {
                const int c = hist[b];
                if (c >= need) {
                    sh_prefix = pfx | ((unsigned)b << shift);
                    sh_need = need;
                    break;
                }
                need -= c;
            }
        }
        __syncthreads();
    }
    const unsigned T = sh_prefix;
    const int r = sh_need;

    for (int j = tid; j < F_DIM; j += 256) {
        const unsigned u = keys[j];
        if (u > T) {
            const int p = atomicAdd(&sel_cnt, 1);
            sidx[p] = j;
        } else if (u == T) {
            const int p = atomicAdd(&eq_cnt, 1);
            if (p < 1024) eqidx[p] = j;
        }
    }
    __syncthreads();

    if (tid == 0) {
        const int m = sel_cnt;
        const int e = eq_cnt < 1024 ? eq_cnt : 1024;
        for (int t2 = 0; t2 < r; ++t2) {
            int best = 0x7FFFFFFF, bi = -1;
            for (int q = 0; q < e; ++q) {
                const int v = eqidx[q];
                if (v >= 0 && v < best) { best = v; bi = q; }
            }
            if (bi >= 0) { eqidx[bi] = -1; sidx[m + t2] = best; }
        }
        sel_cnt = m + r;
        const int n = sel_cnt;
        for (int a2 = 1; a2 < n; ++a2) {
            const int v = sidx[a2];
            int b2 = a2 - 1;
            while (b2 >= 0 && sidx[b2] > v) { sidx[b2 + 1] = sidx[b2]; --b2; }
            sidx[b2 + 1] = v;
        }
    }
    __syncthreads();

    const int total = sel_cnt;
    for (int j = tid; j < total; j += 256) {
        const float v = arow[sidx[j]];
        sval[j] = v > 0.f ? v : 0.f;
    }
    __syncthreads();

    float acc0 = b_dec[tid];
    float acc1 = b_dec[tid + 256];
    float acc2 = b_dec[tid + 512];
    for (int j = 0; j < total; ++j) {
        const float v = sval[j];
        const float* wv = W_dec + (size_t)sidx[j] * D_DIM;
        acc0 = __builtin_fmaf(v, wv[tid],       acc0);
        acc1 = __builtin_fmaf(v, wv[tid + 256], acc1);
        acc2 = __builtin_fmaf(v, wv[tid + 512], acc2);
    }
    float* orow = out + (size_t)row * D_DIM;
    orow[tid] = acc0;
    orow[tid + 256] = acc1;
    orow[tid + 512] = acc2;
}

extern "C" void kernel_launch(void* const* d_in, const int* in_sizes, int n_in,
                              void* d_out, int out_size, void* d_ws, size_t ws_size,
                              hipStream_t stream)
{
    const float* x         = (const float*)d_in[1];
    const float* up_feats  = (const float*)d_in[2];
    const float* W_enc     = (const float*)d_in[3];
    const float* b_enc     = (const float*)d_in[4];
    const float* W_dec     = (const float*)d_in[5];
    const float* b_dec     = (const float*)d_in[6];
    const float* up_W_dec  = (const float*)d_in[7];
    const float* up_b_dec  = (const float*)d_in[8];
    const unsigned char* conn = (const unsigned char*)d_in[9];
    const int* kptr        = (const int*)d_in[10];

    const int BS  = in_sizes[1] / D_DIM;    // 2048
    const int NUP = in_sizes[8] / D_DIM;    // 3

    char* ws = (char*)d_ws;
    size_t off = 0;
    auto alloc = [&](size_t bytes) -> char* {
        off = (off + 255) & ~(size_t)255;
        char* p = ws + off; off += bytes; return p;
    };
    float* approx = (float*)alloc((size_t)BS * F_DIM * 4);
    float* bias2  = (float*)alloc(F_DIM * 4);
    int*   flag   = (int*)alloc(256);
    // packed arrays: logical n elems -> 2n f16 = 4n bytes
    f16* xp   = (f16*)alloc((size_t)BS * D_DIM * 4);
    f16* Wtp  = (f16*)alloc((size_t)F_DIM * D_DIM * 4);
    f16* uwdp = (f16*)alloc((size_t)NUP * F_DIM * D_DIM * 4);
    f16* ufp  = (f16*)alloc((size_t)NUP * BS * F_DIM * 4);

    off = (off + 255) & ~(size_t)255;
    const size_t rem = (ws_size > off) ? ws_size - off : 0;
    int FC = (int)((rem / ((size_t)F_DIM * 4)) / 128 * 128);
    if (FC > F_DIM) FC = F_DIM;
    if (FC < 128) FC = 128;   // ws observed ~3.2GB -> FC = 8192
    f16* vp = (f16*)alloc((size_t)FC * F_DIM * 4);

    detect_kernel<<<1, 256, 0, stream>>>((const int*)conn, flag);
    bias2_kernel<<<F_DIM / 256, 256, 0, stream>>>(W_enc, b_enc, up_b_dec, NUP, bias2);

    split_kernel<<<(unsigned)((size_t)BS * D_DIM / 2048), 256, 0, stream>>>(
        x, xp, (size_t)BS * D_DIM, D_DIM);
    split_kernel<<<(unsigned)((size_t)NUP * F_DIM * D_DIM / 2048), 256, 0, stream>>>(
        up_W_dec, uwdp, (size_t)NUP * F_DIM * D_DIM, D_DIM);
    split_kernel<<<(unsigned)((size_t)NUP * BS * F_DIM / 2048), 256, 0, stream>>>(
        up_feats, ufp, (size_t)NUP * BS * F_DIM, F_DIM);
    transpose_split_kernel<<<F_DIM / 256, 256, 0, stream>>>(W_enc, Wtp);

    // G0: approx = x @ W_enc + bias2
    mfma_gemm<0, 1><<<dim3(F_DIM / BMN, BS / BMN), 256, 0, stream>>>(
        xp, Wtp, approx, F_DIM, nullptr, bias2,
        nullptr, 0, flag, D_DIM, 0);

    for (int i = 0; i < NUP; ++i) {
        for (int fc = 0; fc < F_DIM; fc += FC) {
            const int chunk = (F_DIM - fc) < FC ? (F_DIM - fc) : FC;
            // G1: virtT[fd in chunk][fu] = (W_encT @ up_W_dec[i]^T) * maskT
            mfma_gemm<1, 1><<<dim3(F_DIM / BMN, chunk / BMN), 256, 0, stream>>>(
                Wtp + (size_t)fc * (2 * D_DIM),
                uwdp + (size_t)i * F_DIM * (2 * D_DIM),
                nullptr, 0, vp, nullptr,
                conn, i, flag, D_DIM, fc);
            // G2: approx[:, fc:fc+chunk] += up_feats[i] @ virt  (K = 8192 fu)
            // NT=2 strips: grid 32x16 = 512 blocks = one co-resident
            // generation -> vp fetched once (compulsory)
            mfma_gemm<2, 2><<<dim3(chunk / (BMN * 2), BS / BMN), 256, 0, stream>>>(
                ufp + (size_t)i * BS * (2 * F_DIM),
                vp,
                approx + fc, F_DIM, nullptr, nullptr,
                nullptr, 0, flag, F_DIM, 0);
        }
    }

    topk_decode_kernel<<<BS, 256, 0, stream>>>(
        approx, W_dec, b_dec, kptr, (float*)d_out);
}

// Round 10
// 3797.631 us; speedup vs baseline: 1.2263x; 1.0524x over previous
//
#include <hip/hip_runtime.h>
#include <hip/hip_bf16.h>

// SCAE forward on MI355X — f16 split-MFMA (Ootomo 3-product) pipeline.
//   v = h + l/2048 (f16 h,l; subnormal-guarded)  =>
//   A@B = Ah@Bh + (Ah@Bl + Al@Bh)/2048   (drop 2^-22 term)
// All GEMMs are A[M][K] x BT[N][K] row-major:
//   G0: approx = x @ W_enc       A=x_pk,   BT=W_encT_pk,   C=f32 +bias2
//   G1: virtT  = W_encT @ uWdT   A=Wt_pk,  BT=up_W_dec_pk, C=packed f16, mask in epilogue
//   G2: approx+= up_feats @ virt A=uf_pk,  BT=virtT_pk,    C=f32 +=
// Then exact radix top-k (ties->lowest index), relu, sparse decode.
//
// R10 = R6 (best, 3786us) + ONE change: G2 grid axes swapped (bm from
// blockIdx.x, bn from blockIdx.y). x-fastest dispatch then makes each
// co-resident generation = {all 16 bm x half the bn range}: working set
// = vp/2 (128MB) + A (64MB) < L3 256MB -> vp fetched once (compulsory),
// vs R6's generation = {8 bm x all bn} whose 300MB working set thrashed
// vp and re-fetched it (FETCH 1.1GB, the remaining G2 overhead).

#define D_DIM 768
#define F_DIM 8192

typedef _Float16 f16;
typedef _Float16 f16x8 __attribute__((ext_vector_type(8)));
typedef float f32x4 __attribute__((ext_vector_type(4)));

#define BMN 128
#define BUFB 32768    // one K-tile: A 16KB + B 16KB (128 rows x 128B each)
#define PLNB 16384    // per-matrix region: 128 rows x 128B ([h|l] packed, XOR-8 swizzled)

__device__ inline void split_f32(float v, f16& h, f16& l) {
    float hf = (float)(f16)v;
    if (__builtin_fabsf(hf) < 6.1035156e-5f) hf = 0.f;   // keep h MFMA-normal
    h = (f16)hf;
    l = (f16)((v - hf) * 2048.0f);
}

// MODE 0: C = comb + bias[col]             (f32)
// MODE 1: Vp = packed_split(comb * mask)   (f16, row = 2*F_DIM elems)
// MODE 2: C += comb                        (f32)  [grid axes SWAPPED]
template<int MODE>
__global__ __launch_bounds__(256, 2)
void mfma_gemm(const f16* __restrict__ Ap,     // packed, row stride 2K f16
               const f16* __restrict__ Bp,     // packed BT, row stride 2K f16
               float* __restrict__ C, int ldc,
               f16* __restrict__ Vp,
               const float* __restrict__ bias,
               const unsigned char* __restrict__ conn, int upIdx,
               const int* __restrict__ flagp,
               int K, int fdBase)
{
    __shared__ char lds[2 * BUFB];   // double-buffered K-tile
    const int tid = threadIdx.x;
    // MODE 2: bm varies fastest across dispatch -> generation working set
    // = all A + contiguous half of vp -> L3-resident, vp fetched once.
    const int bm = (MODE == 2 ? blockIdx.x : blockIdx.y) * BMN;
    const int bn = (MODE == 2 ? blockIdx.y : blockIdx.x) * BMN;

    const int w  = tid >> 6;
    const int l  = tid & 63;
    const int wr = (w >> 1) * 64;   // wave row origin
    const int wc = (w & 1) * 64;    // wave col origin

    // Staging: 2048 chunks of 16B per K-tile, 8/thread (c = tid + 256j).
    // chunk c: matrix p=c>>10 (0=A,1=B), row r=(c>>3)&127, phys slot sp=c&7.
    // logical slot = sp ^ (r&7) (XOR-8, involution); row source bytes are
    // CONTIGUOUS 128B = [h k-slots 0..3 | l k-slots 4..7]. LDS dest linear.
    const char* gsrc[8];
    #pragma unroll
    for (int j = 0; j < 8; ++j) {
        const int c = tid + 256 * j;
        const int p = c >> 10;
        const int q = c & 1023;
        const int r = q >> 3;
        const int sp = q & 7;
        const int slog = sp ^ (r & 7);
        const f16* base = p ? Bp : Ap;
        const int row0 = p ? bn : bm;
        gsrc[j] = (const char*)base + (size_t)(row0 + r) * ((size_t)K * 4)
                  + slog * 16;
    }

    #define STAGE(BUFSEL)                                                     \
        _Pragma("unroll")                                                     \
        for (int j = 0; j < 8; ++j) {                                         \
            __builtin_amdgcn_global_load_lds(                                 \
                (const __attribute__((address_space(1))) void*)gsrc[j],       \
                (__attribute__((address_space(3))) void*)                     \
                    (lds + (BUFSEL) * BUFB + (tid + 256 * j) * 16),           \
                16, 0, 0);                                                    \
            gsrc[j] += 128;   /* next 32-k packed block */                    \
        }

    f32x4 accH[4][4], accM[4][4];
    const f32x4 zero = {0.f, 0.f, 0.f, 0.f};
    #pragma unroll
    for (int a = 0; a < 4; ++a)
        #pragma unroll
        for (int b = 0; b < 4; ++b) { accH[a][b] = zero; accM[a][b] = zero; }

    const int steps = K >> 5;
    const int fr = l & 15;
    const int ks = l >> 4;          // k-slot 0..3

    // Hoisted loop-invariant LDS read byte-offsets (XOR-swizzle math ONCE).
    int offAH[4], offBH[4], offAL[4], offBL[4];
    #pragma unroll
    for (int f = 0; f < 4; ++f) {
        const int ra = wr + f * 16 + fr;
        const int rb = wc + f * 16 + fr;
        offAH[f] = ra * 128 + ((ks ^ (ra & 7)) * 16);
        offAL[f] = ra * 128 + (((4 + ks) ^ (ra & 7)) * 16);
        offBH[f] = PLNB + rb * 128 + ((ks ^ (rb & 7)) * 16);
        offBL[f] = PLNB + rb * 128 + (((4 + ks) ^ (rb & 7)) * 16);
    }

    STAGE(0);
    int cur = 0;
    for (int t = 0; t < steps; ++t) {
        // buf[cur]'s loads were issued one phase ago (hidden under MFMAs)
        asm volatile("s_waitcnt vmcnt(0)" ::: "memory");
        __syncthreads();

        const char* Lb = lds + cur * BUFB;
        // ---- read h-fragments (8 reads) ----
        f16x8 ah[4], bh[4];
        #pragma unroll
        for (int mf = 0; mf < 4; ++mf) ah[mf] = *(const f16x8*)(Lb + offAH[mf]);
        #pragma unroll
        for (int nf = 0; nf < 4; ++nf) bh[nf] = *(const f16x8*)(Lb + offBH[nf]);

        // ---- stage next tile (drained at next iter's top) ----
        if (t + 1 < steps) STAGE(cur ^ 1);

        // ---- read l-fragments (8 reads; overlap H-MFMAs via lgkmcnt) ----
        f16x8 al[4], bl[4];
        #pragma unroll
        for (int nf = 0; nf < 4; ++nf) bl[nf] = *(const f16x8*)(Lb + offBL[nf]);
        #pragma unroll
        for (int mf = 0; mf < 4; ++mf) al[mf] = *(const f16x8*)(Lb + offAL[mf]);

        // ---- H phase: 16 MFMAs ----
        __builtin_amdgcn_s_setprio(1);
        #pragma unroll
        for (int nf = 0; nf < 4; ++nf)
            #pragma unroll
            for (int mf = 0; mf < 4; ++mf)
                accH[mf][nf] = __builtin_amdgcn_mfma_f32_16x16x32_f16(
                    ah[mf], bh[nf], accH[mf][nf], 0, 0, 0);
        __builtin_amdgcn_s_setprio(0);

        // ---- M phase: 32 MFMAs ----
        __builtin_amdgcn_s_setprio(1);
        #pragma unroll
        for (int nf = 0; nf < 4; ++nf)
            #pragma unroll
            for (int mf = 0; mf < 4; ++mf)
                accM[mf][nf] = __builtin_amdgcn_mfma_f32_16x16x32_f16(
                    ah[mf], bl[nf], accM[mf][nf], 0, 0, 0);
        #pragma unroll
        for (int mf = 0; mf < 4; ++mf)
            #pragma unroll
            for (int nf = 0; nf < 4; ++nf)
                accM[mf][nf] = __builtin_amdgcn_mfma_f32_16x16x32_f16(
                    al[mf], bh[nf], accM[mf][nf], 0, 0, 0);
        __builtin_amdgcn_s_setprio(0);

        cur ^= 1;
    }
    #undef STAGE

    const float MS = 4.8828125e-4f;   // 1/2048
    const int flag = (MODE == 1) ? *flagp : 0;

    #pragma unroll
    for (int mf = 0; mf < 4; ++mf) {
        const int row0 = wr + mf * 16 + (l >> 4) * 4;   // local row of reg 0
        #pragma unroll
        for (int nf = 0; nf < 4; ++nf) {
            const int col = wc + nf * 16 + (l & 15);
            float v[4];
            #pragma unroll
            for (int rr = 0; rr < 4; ++rr)
                v[rr] = accH[mf][nf][rr] + accM[mf][nf][rr] * MS;

            if (MODE == 0) {
                const float bb = bias[bn + col];
                #pragma unroll
                for (int rr = 0; rr < 4; ++rr)
                    C[(size_t)(bm + row0 + rr) * ldc + (bn + col)] = v[rr] + bb;
            } else if (MODE == 2) {
                #pragma unroll
                for (int rr = 0; rr < 4; ++rr) {
                    float* cp = &C[(size_t)(bm + row0 + rr) * ldc + (bn + col)];
                    *cp = *cp + v[rr];
                }
            } else {
                const size_t fu = (size_t)(bn + col);
                const size_t fd0 = (size_t)(fdBase + bm + row0);
                int m[4];
                if (flag == 1) {
                    const int4 mm = *(const int4*)((const int*)conn +
                        (size_t)upIdx * F_DIM * F_DIM + fu * F_DIM + fd0);
                    m[0] = mm.x; m[1] = mm.y; m[2] = mm.z; m[3] = mm.w;
                } else if (flag == 0) {
                    const uchar4 mm = *(const uchar4*)(conn +
                        (size_t)upIdx * F_DIM * F_DIM + fu * F_DIM + fd0);
                    m[0] = mm.x; m[1] = mm.y; m[2] = mm.z; m[3] = mm.w;
                } else if (flag == 2) {
                    const long long* pp = (const long long*)conn +
                        (size_t)upIdx * F_DIM * F_DIM + fu * F_DIM + fd0;
                    m[0] = (int)pp[0]; m[1] = (int)pp[1];
                    m[2] = (int)pp[2]; m[3] = (int)pp[3];
                } else {
                    const float4 mm = *(const float4*)((const float*)conn +
                        (size_t)upIdx * F_DIM * F_DIM + fu * F_DIM + fd0);
                    m[0] = mm.x != 0.f; m[1] = mm.y != 0.f;
                    m[2] = mm.z != 0.f; m[3] = mm.w != 0.f;
                }
                // packed write: row fd, k=fu -> fd*2F + (fu>>5)*64 + (fu&31)
                const size_t kblk = (fu >> 5) * 64 + (fu & 31);
                #pragma unroll
                for (int rr = 0; rr < 4; ++rr) {
                    const float vv = m[rr] ? v[rr] : 0.f;
                    f16 hh, ll;
                    split_f32(vv, hh, ll);
                    const size_t o = (size_t)(bm + row0 + rr) * (2 * F_DIM) + kblk;
                    Vp[o] = hh; Vp[o + 32] = ll;
                }
            }
        }
    }
}

// elementwise split into packed layout: row r of K -> 2K f16, blocks of
// [32 h | 32 l]. 8 contiguous k per thread (stay within one 32-block).
__global__ __launch_bounds__(256)
void split_kernel(const float* __restrict__ src, f16* __restrict__ dst,
                  size_t n, int K)
{
    const size_t e = ((size_t)blockIdx.x * 256 + threadIdx.x) * 8;
    if (e >= n) return;
    const size_t r = e / (size_t)K;
    const int k = (int)(e - r * (size_t)K);
    const float4 a = *(const float4*)(src + e);
    const float4 b = *(const float4*)(src + e + 4);
    f16 hv[8], lv[8];
    const float s[8] = {a.x, a.y, a.z, a.w, b.x, b.y, b.z, b.w};
    #pragma unroll
    for (int i = 0; i < 8; ++i) split_f32(s[i], hv[i], lv[i]);
    const size_t base = r * (size_t)(2 * K) + (size_t)((k >> 5) * 64 + (k & 31));
    *(f16x8*)(dst + base)      = *(const f16x8*)hv;
    *(f16x8*)(dst + base + 32) = *(const f16x8*)lv;
}

// W_enc [768][8192] -> packed W_encT rows f (K=768); reads coalesced along f
__global__ __launch_bounds__(256)
void transpose_split_kernel(const float* __restrict__ W, f16* __restrict__ dst)
{
    const int f = blockIdx.x * 256 + threadIdx.x;
    for (int dc = 0; dc < D_DIM / 8; ++dc) {
        const int k = dc * 8;
        f16 hv[8], lv[8];
        #pragma unroll
        for (int j = 0; j < 8; ++j)
            split_f32(W[(size_t)(k + j) * F_DIM + f], hv[j], lv[j]);
        const size_t base = (size_t)f * (2 * D_DIM) + (k >> 5) * 64 + (k & 31);
        *(f16x8*)(dst + base)      = *(const f16x8*)hv;
        *(f16x8*)(dst + base + 32) = *(const f16x8*)lv;
    }
}

// conn_mask storage-layout detection: 0=u8, 1=i32, 2=i64, 3=f32
__global__ void detect_kernel(const int* __restrict__ conn, int* __restrict__ flag)
{
    __shared__ int not01, notf01, odd_nz;
    if (threadIdx.x == 0) { not01 = 0; notf01 = 0; odd_nz = 0; }
    __syncthreads();
    const int4 v = ((const int4*)conn)[threadIdx.x];
    const unsigned a[4] = {(unsigned)v.x, (unsigned)v.y,
                           (unsigned)v.z, (unsigned)v.w};
    int l_not01 = 0, l_notf = 0;
    #pragma unroll
    for (int i = 0; i < 4; ++i) {
        if (a[i] > 1u) l_not01 = 1;
        if (a[i] != 0u && a[i] != 0x3F800000u) l_notf = 1;
    }
    if (l_not01) atomicOr(&not01, 1);
    if (l_notf)  atomicOr(&notf01, 1);
    if (a[1] | a[3]) atomicOr(&odd_nz, 1);
    __syncthreads();
    if (threadIdx.x == 0) {
        int f;
        if (!not01)        f = odd_nz ? 1 : 2;
        else if (!notf01)  f = 3;
        else               f = 0;
        *flag = f;
    }
}

__global__ void bias2_kernel(const float* __restrict__ W_enc,
                             const float* __restrict__ b_enc,
                             const float* __restrict__ up_b_dec,
                             int nup, float* __restrict__ bias2)
{
    const int g = blockIdx.x * 256 + threadIdx.x;
    if (g >= F_DIM) return;
    float s = b_enc[g];
    for (int d = 0; d < D_DIM; ++d) {
        float ub = 0.f;
        for (int i = 0; i < nup; ++i) ub += up_b_dec[i * D_DIM + d];
        s = __builtin_fmaf(ub, W_enc[(size_t)d * F_DIM + g], s);
    }
    bias2[g] = s;
}

// exact radix top-k (ties -> lowest index), relu, sparse decode
__global__ __launch_bounds__(256)
void topk_decode_kernel(const float* __restrict__ approx,
                        const float* __restrict__ W_dec,
                        const float* __restrict__ b_dec,
                        const int* __restrict__ kptr,
                        float* __restrict__ out)
{
    __shared__ unsigned keys[F_DIM];
    __shared__ int hist[256];
    __shared__ unsigned sh_prefix;
    __shared__ int sh_need;
    __shared__ int sel_cnt, eq_cnt;
    __shared__ int sidx[128];
    __shared__ float sval[128];
    __shared__ int eqidx[1024];

    const int tid = threadIdx.x;
    const int row = blockIdx.x;
    const int k = *kptr;
    const float* arow = approx + (size_t)row * F_DIM;

    for (int j = tid; j < F_DIM; j += 256) {
        unsigned u = __float_as_uint(arow[j]);
        u = (u & 0x80000000u) ? ~u : (u | 0x80000000u);
        keys[j] = u;
    }
    if (tid == 0) { sh_prefix = 0u; sh_need = k; sel_cnt = 0; eq_cnt = 0; }
    __syncthreads();

    for (int shift = 24; shift >= 0; shift -= 8) {
        if (tid < 256) hist[tid] = 0;
        __syncthreads();
        const unsigned pfx = sh_prefix;
        for (int j = tid; j < F_DIM; j += 256) {
            const unsigned u = keys[j];
            const bool match =
                (shift == 24) || ((u >> (shift + 8)) == (pfx >> (shift + 8)));
            if (match) atomicAdd(&hist[(u >> shift) & 255], 1);
        }
        __syncthreads();
        if (tid == 0) {
            int need = sh_need;
            for (int b = 255; b >= 0; --b) {
                const int c = hist[b];
                if (c >= need) {
                    sh_prefix = pfx | ((unsigned)b << shift);
                    sh_need = need;
                    break;
                }
                need -= c;
            }
        }
        __syncthreads();
    }
    const unsigned T = sh_prefix;
    const int r = sh_need;

    for (int j = tid; j < F_DIM; j += 256) {
        const unsigned u = keys[j];
        if (u > T) {
            const int p = atomicAdd(&sel_cnt, 1);
            sidx[p] = j;
        } else if (u == T) {
            const int p = atomicAdd(&eq_cnt, 1);
            if (p < 1024) eqidx[p] = j;
        }
    }
    __syncthreads();

    if (tid == 0) {
        const int m = sel_cnt;
        const int e = eq_cnt < 1024 ? eq_cnt : 1024;
        for (int t2 = 0; t2 < r; ++t2) {
            int best = 0x7FFFFFFF, bi = -1;
            for (int q = 0; q < e; ++q) {
                const int v = eqidx[q];
                if (v >= 0 && v < best) { best = v; bi = q; }
            }
            if (bi >= 0) { eqidx[bi] = -1; sidx[m + t2] = best; }
        }
        sel_cnt = m + r;
        const int n = sel_cnt;
        for (int a2 = 1; a2 < n; ++a2) {
            const int v = sidx[a2];
            int b2 = a2 - 1;
            while (b2 >= 0 && sidx[b2] > v) { sidx[b2 + 1] = sidx[b2]; --b2; }
            sidx[b2 + 1] = v;
        }
    }
    __syncthreads();

    const int total = sel_cnt;
    for (int j = tid; j < total; j += 256) {
        const float v = arow[sidx[j]];
        sval[j] = v > 0.f ? v : 0.f;
    }
    __syncthreads();

    float acc0 = b_dec[tid];
    float acc1 = b_dec[tid + 256];
    float acc2 = b_dec[tid + 512];
    for (int j = 0; j < total; ++j) {
        const float v = sval[j];
        const float* wv = W_dec + (size_t)sidx[j] * D_DIM;
        acc0 = __builtin_fmaf(v, wv[tid],       acc0);
        acc1 = __builtin_fmaf(v, wv[tid + 256], acc1);
        acc2 = __builtin_fmaf(v, wv[tid + 512], acc2);
    }
    float* orow = out + (size_t)row * D_DIM;
    orow[tid] = acc0;
    orow[tid + 256] = acc1;
    orow[tid + 512] = acc2;
}

extern "C" void kernel_launch(void* const* d_in, const int* in_sizes, int n_in,
                              void* d_out, int out_size, void* d_ws, size_t ws_size,
                              hipStream_t stream)
{
    const float* x         = (const float*)d_in[1];
    const float* up_feats  = (const float*)d_in[2];
    const float* W_enc     = (const float*)d_in[3];
    const float* b_enc     = (const float*)d_in[4];
    const float* W_dec     = (const float*)d_in[5];
    const float* b_dec     = (const float*)d_in[6];
    const float* up_W_dec  = (const float*)d_in[7];
    const float* up_b_dec  = (const float*)d_in[8];
    const unsigned char* conn = (const unsigned char*)d_in[9];
    const int* kptr        = (const int*)d_in[10];

    const int BS  = in_sizes[1] / D_DIM;    // 2048
    const int NUP = in_sizes[8] / D_DIM;    // 3

    char* ws = (char*)d_ws;
    size_t off = 0;
    auto alloc = [&](size_t bytes) -> char* {
        off = (off + 255) & ~(size_t)255;
        char* p = ws + off; off += bytes; return p;
    };
    float* approx = (float*)alloc((size_t)BS * F_DIM * 4);
    float* bias2  = (float*)alloc(F_DIM * 4);
    int*   flag   = (int*)alloc(256);
    // packed arrays: logical n elems -> 2n f16 = 4n bytes
    f16* xp   = (f16*)alloc((size_t)BS * D_DIM * 4);
    f16* Wtp  = (f16*)alloc((size_t)F_DIM * D_DIM * 4);
    f16* uwdp = (f16*)alloc((size_t)NUP * F_DIM * D_DIM * 4);
    f16* ufp  = (f16*)alloc((size_t)NUP * BS * F_DIM * 4);

    off = (off + 255) & ~(size_t)255;
    const size_t rem = (ws_size > off) ? ws_size - off : 0;
    int FC = (int)((rem / ((size_t)F_DIM * 4)) / 128 * 128);
    if (FC > F_DIM) FC = F_DIM;
    if (FC < 128) FC = 128;   // ws observed ~3.2GB -> FC = 8192
    f16* vp = (f16*)alloc((size_t)FC * F_DIM * 4);

    detect_kernel<<<1, 256, 0, stream>>>((const int*)conn, flag);
    bias2_kernel<<<F_DIM / 256, 256, 0, stream>>>(W_enc, b_enc, up_b_dec, NUP, bias2);

    split_kernel<<<(unsigned)((size_t)BS * D_DIM / 2048), 256, 0, stream>>>(
        x, xp, (size_t)BS * D_DIM, D_DIM);
    split_kernel<<<(unsigned)((size_t)NUP * F_DIM * D_DIM / 2048), 256, 0, stream>>>(
        up_W_dec, uwdp, (size_t)NUP * F_DIM * D_DIM, D_DIM);
    split_kernel<<<(unsigned)((size_t)NUP * BS * F_DIM / 2048), 256, 0, stream>>>(
        up_feats, ufp, (size_t)NUP * BS * F_DIM, F_DIM);
    transpose_split_kernel<<<F_DIM / 256, 256, 0, stream>>>(W_enc, Wtp);

    // G0: approx = x @ W_enc + bias2
    mfma_gemm<0><<<dim3(F_DIM / BMN, BS / BMN), 256, 0, stream>>>(
        xp, Wtp, approx, F_DIM, nullptr, bias2,
        nullptr, 0, flag, D_DIM, 0);

    for (int i = 0; i < NUP; ++i) {
        for (int fc = 0; fc < F_DIM; fc += FC) {
            const int chunk = (F_DIM - fc) < FC ? (F_DIM - fc) : FC;
            // G1: virtT[fd in chunk][fu] = (W_encT @ up_W_dec[i]^T) * maskT
            mfma_gemm<1><<<dim3(F_DIM / BMN, chunk / BMN), 256, 0, stream>>>(
                Wtp + (size_t)fc * (2 * D_DIM),
                uwdp + (size_t)i * F_DIM * (2 * D_DIM),
                nullptr, 0, vp, nullptr,
                conn, i, flag, D_DIM, fc);
            // G2: approx[:, fc:fc+chunk] += up_feats[i] @ virt  (K = 8192 fu)
            // grid axes SWAPPED: x = bm (16), y = bn (64)
            mfma_gemm<2><<<dim3(BS / BMN, chunk / BMN), 256, 0, stream>>>(
                ufp + (size_t)i * BS * (2 * F_DIM),
                vp,
                approx + fc, F_DIM, nullptr, nullptr,
                nullptr, 0, flag, F_DIM, 0);
        }
    }

    topk_decode_kernel<<<BS, 256, 0, stream>>>(
        approx, W_dec, b_dec, kptr, (float*)d_out);
}